// Round 2
// baseline (231.177 us; speedup 1.0000x reference)
//
#include <hip/hip_runtime.h>
#include <hip/hip_bf16.h>
#include <math.h>

#define Bx 8
#define Cx 512
#define Dx 256
#define Tx 2048
#define EPSx 1e-5f

typedef _Float16 h16;
typedef __attribute__((ext_vector_type(8))) _Float16 h16x8;
typedef __attribute__((ext_vector_type(8))) short s16x8;
typedef __attribute__((ext_vector_type(4))) float f32x4;

typedef __attribute__((address_space(3))) unsigned int lds_u32;
typedef __attribute__((address_space(1))) const unsigned int glb_u32;

// async 16B global -> LDS DMA. ldsp must be wave-uniform; HW adds lane*16.
__device__ __forceinline__ void cp16(void* ldsp, const void* g) {
    __builtin_amdgcn_global_load_lds((glb_u32*)g, (lds_u32*)ldsp, 16, 0, 0);
}

// ---------------------------------------------------------------------------
// MFMA GEMM core: acc[m][n] = sum_k A[m][k]*B[n][k], 2-byte dtypes (f16/bf16),
// tile 128 x TN (TN=128 or 64), BK=64 (0-conflict LDS layout), 4 waves (2x2),
// global_load_lds staging with XOR swizzle.
// DBUF: 2-phase double-buffered K-loop (T3 minimal recipe): issue STAGE(next)
//   before compute(cur); one raw vmcnt(0)+s_barrier per tile. Used where TLP
//   is thin (<=2-3 blocks/CU) or K is short.
// Grid: 1-D, batch->XCD swizzle: b = id & 7;
// rr = id >> 3; m0 = (rr % mBlk)*128; n0 = (rr / mBlk)*TN.
// Epilogue by MODE:
//   0: f16 out, + optional biasM[row] + biasN[col]                (projection)
//   1: bf16 out = (acc + optional biasM[row]) * (1/Z[b*N+col])    (gT' = g/Z)
//   2: bf16 out = exp(acc); atomicAdd Z[b*N+col] += col sums      (logits)
//   3: f16 out = acc + biasN[col]; atomicAdd Cp[col]+=sum(v),
//      Z[col]+=sum(v^2) (fused BatchNorm stats)                   (h GEMM)
// ---------------------------------------------------------------------------
template<int MODE, bool BF, int TN, bool DBUF>
__global__ __launch_bounds__(256, 4)
void gemm_mf(const h16* __restrict__ A, long aBatch, int lda,
             const h16* __restrict__ B, long bBatch, int ldb,
             void* __restrict__ C, long cBatch, int ldc,
             float* __restrict__ Cp, float* __restrict__ Z,
             int M, int N, int K, int mBlk,
             const float* __restrict__ biasM, const float* __restrict__ biasN) {
    constexpr int NJ = TN / 32;          // B-frags per wave (n-dir)
    constexpr int NB = DBUF ? 2 : 1;
    __shared__ h16 As[NB * 128 * 64];
    __shared__ h16 Bs[NB * TN * 64];
    const int tid  = threadIdx.x;
    const int lane = tid & 63, wid = tid >> 6;
    const int wm = (wid & 1) * 64, wn = (wid >> 1) * (TN / 2);
    const int lm = lane & 15, quad = lane >> 4;
    const unsigned id = blockIdx.x;
    const int b = id & 7;
    const unsigned rr = id >> 3;
    const int m0 = (rr % (unsigned)mBlk) * 128;
    const int n0 = (rr / (unsigned)mBlk) * TN;
    const h16* Ab = A + (size_t)b * aBatch + (size_t)m0 * lda;
    const h16* Bb = B + (size_t)b * bBatch + (size_t)n0 * ldb;

    const int srow  = tid >> 3;                 // row within 32-row group
    const int sclog = (tid & 7) ^ (srow & 7);   // logical k-chunk (XOR swizzle)

    f32x4 acc[4][NJ] = {};

    auto stage = [&](int buf, int k0) {
        char* lA = (char*)As + buf * 16384 + (tid & ~63) * 16;
        char* lB = (char*)Bs + buf * (TN * 128) + (tid & ~63) * 16;
#pragma unroll
        for (int i = 0; i < 4; i++) {
            int r = srow + 32 * i;
            cp16(lA + i * 4096, Ab + (size_t)r * lda + k0 + sclog * 8);
        }
#pragma unroll
        for (int i = 0; i < TN / 32; i++) {
            int r = srow + 32 * i;
            cp16(lB + i * 4096, Bb + (size_t)r * ldb + k0 + sclog * 8);
        }
    };
    auto compute = [&](int buf) {
        const h16* Ac = As + buf * (128 * 64);
        const h16* Bc = Bs + buf * (TN * 64);
#pragma unroll
        for (int ks = 0; ks < 2; ks++) {
            s16x8 af[4], bf4[NJ];
#pragma unroll
            for (int i = 0; i < 4; i++) {
                int row = wm + 16 * i + lm;
                int st = (ks * 4 + quad) ^ (lm & 7);
                af[i] = *(const s16x8*)(Ac + row * 64 + st * 8);
            }
#pragma unroll
            for (int j = 0; j < NJ; j++) {
                int row = wn + 16 * j + lm;
                int st = (ks * 4 + quad) ^ (lm & 7);
                bf4[j] = *(const s16x8*)(Bc + row * 64 + st * 8);
            }
#pragma unroll
            for (int i = 0; i < 4; i++)
#pragma unroll
                for (int j = 0; j < NJ; j++) {
                    if constexpr (BF)
                        acc[i][j] = __builtin_amdgcn_mfma_f32_16x16x32_bf16(
                            af[i], bf4[j], acc[i][j], 0, 0, 0);
                    else
                        acc[i][j] = __builtin_amdgcn_mfma_f32_16x16x32_f16(
                            __builtin_bit_cast(h16x8, af[i]),
                            __builtin_bit_cast(h16x8, bf4[j]), acc[i][j], 0, 0, 0);
                }
        }
    };

    if constexpr (!DBUF) {
        for (int k0 = 0; k0 < K; k0 += 64) {
            __syncthreads();   // all waves done reading previous tile
            stage(0, k0);
            __syncthreads();   // drains vmcnt(0): tile resident
            compute(0);
        }
    } else {
        stage(0, 0);
        asm volatile("s_waitcnt vmcnt(0)" ::: "memory");
        __builtin_amdgcn_s_barrier();
        int cur = 0;
        for (int k0 = 0; k0 < K; k0 += 64) {
            if (k0 + 64 < K) stage(cur ^ 1, k0 + 64);  // prefetch next tile
            compute(cur);                               // hides load latency
            asm volatile("s_waitcnt vmcnt(0)" ::: "memory");
            __builtin_amdgcn_s_barrier();
            cur ^= 1;
        }
    }

    // epilogue: C/D layout col=lane&15, row=quad*4+reg
    if constexpr (MODE == 0) {
        h16* Cb = (h16*)C + (size_t)b * cBatch;
#pragma unroll
        for (int i = 0; i < 4; i++)
#pragma unroll
            for (int j = 0; j < NJ; j++) {
                int row = m0 + wm + 16 * i + quad * 4;
                int col = n0 + wn + 16 * j + lm;
                float bN = biasN ? biasN[col] : 0.0f;
#pragma unroll
                for (int r = 0; r < 4; r++) {
                    float v = acc[i][j][r] + bN;
                    if (biasM) v += biasM[row + r];
                    Cb[(size_t)(row + r) * ldc + col] = (h16)v;
                }
            }
    } else if constexpr (MODE == 1) {
        __hip_bfloat16* Cb = (__hip_bfloat16*)C + (size_t)b * cBatch;
#pragma unroll
        for (int j = 0; j < NJ; j++) {
            int col = n0 + wn + 16 * j + lm;
            float iz = 1.0f / Z[(size_t)b * N + col];
#pragma unroll
            for (int i = 0; i < 4; i++) {
                int row = m0 + wm + 16 * i + quad * 4;
#pragma unroll
                for (int r = 0; r < 4; r++) {
                    float v = acc[i][j][r];
                    if (biasM) v += biasM[row + r];
                    Cb[(size_t)(row + r) * ldc + col] = __float2bfloat16(v * iz);
                }
            }
        }
    } else if constexpr (MODE == 2) {
        __syncthreads();                       // fragments consumed
        float* Zl = (float*)As;
        if (tid < TN) Zl[tid] = 0.0f;
        __syncthreads();
        __hip_bfloat16* Cb = (__hip_bfloat16*)C + (size_t)b * cBatch;
#pragma unroll
        for (int j = 0; j < NJ; j++) {
            int cl = wn + 16 * j + lm;
            int col = n0 + cl;
            float zp = 0.0f;
#pragma unroll
            for (int i = 0; i < 4; i++) {
                int row = m0 + wm + 16 * i + quad * 4;
#pragma unroll
                for (int r = 0; r < 4; r++) {
                    float e = __expf(acc[i][j][r]);
                    zp += e;
                    Cb[(size_t)(row + r) * ldc + col] = __float2bfloat16(e);
                }
            }
            atomicAdd(&Zl[cl], zp);
        }
        __syncthreads();
        if (tid < TN) atomicAdd(&Z[(size_t)b * N + n0 + tid], Zl[tid]);
    } else {  // MODE 3: f16 out + biasN, fused BN sum/sumsq atomics
        __syncthreads();                       // fragments consumed
        float* Sl = (float*)As;                // [0:TN) col sums
        float* Sq = Sl + TN;                   // [TN:2TN) col sumsq
        if (tid < 2 * TN) Sl[tid] = 0.0f;
        __syncthreads();
        h16* Cb = (h16*)C + (size_t)b * cBatch;
#pragma unroll
        for (int j = 0; j < NJ; j++) {
            int cl = wn + 16 * j + lm;
            int col = n0 + cl;
            float bN = biasN[col];
            float s = 0.0f, q = 0.0f;
#pragma unroll
            for (int i = 0; i < 4; i++) {
                int row = m0 + wm + 16 * i + quad * 4;
#pragma unroll
                for (int r = 0; r < 4; r++) {
                    float v = acc[i][j][r] + bN;
                    s += v;
                    q = fmaf(v, v, q);
                    Cb[(size_t)(row + r) * ldc + col] = (h16)v;
                }
            }
            atomicAdd(&Sl[cl], s);
            atomicAdd(&Sq[cl], q);
        }
        __syncthreads();
        if (tid < TN) {
            atomicAdd(&Cp[n0 + tid], Sl[tid]);
            atomicAdd(&Z[n0 + tid], Sq[tid]);
        }
    }
}

// ---------------------------------------------------------------------------
// Fused prep: z<8  -> inpt[b][c][t] fp32 -> xT[b][t][c] f16 (64x64 transpose)
//             z==8 -> weights->f16 concat, bias3, Z/psum/pssq zero-init.
// ---------------------------------------------------------------------------
__global__ __launch_bounds__(256)
void conv_prep(const float* __restrict__ inpt, h16* __restrict__ xT,
               const float* __restrict__ w0, const float* __restrict__ w1,
               const float* __restrict__ w2, const float* __restrict__ w3,
               const float* __restrict__ tb, const float* __restrict__ pb,
               const float* __restrict__ gb,
               h16* __restrict__ dst, float* __restrict__ bias3,
               float* __restrict__ Z, float* __restrict__ psum,
               float* __restrict__ pssq) {
    const int tid = threadIdx.x;
    if (blockIdx.z == 8) {
        int bx = blockIdx.y * 32 + blockIdx.x;          // 0..255
        // weights: 131072 float4 total, 512 per block
#pragma unroll
        for (int rep = 0; rep < 2; rep++) {
            int idx4 = bx * 512 + rep * 256 + tid;
            int arr = idx4 >> 15, local4 = idx4 & 32767;
            const float* srcs[4] = {w0, w1, w2, w3};
            float4 v = ((const float4*)srcs[arr])[local4];
            h16 o[4] = {(h16)v.x, (h16)v.y, (h16)v.z, (h16)v.w};
            *(uint2*)(dst + (size_t)arr * 131072 + (size_t)local4 * 4) = *(uint2*)o;
        }
        if (bx < 64) Z[bx * 256 + tid] = 0.0f;          // 16384 floats
        if (bx == 64) bias3[tid] = tb[tid];
        if (bx == 65) bias3[256 + tid] = pb[tid];
        if (bx == 66) bias3[512 + tid] = gb[tid];
        if (bx == 67) {
            psum[tid] = 0.0f; psum[tid + 256] = 0.0f;
            pssq[tid] = 0.0f; pssq[tid + 256] = 0.0f;
        }
        return;
    }
    __shared__ float lds[64][68];
    const int b = blockIdx.z;
    const int t0 = blockIdx.x * 64, c0 = blockIdx.y * 64;
    const int q = tid >> 4, k = tid & 15;
    const float* ib = inpt + (size_t)b * Cx * Tx;
#pragma unroll
    for (int i = 0; i < 4; i++) {
        int c = q + 16 * i;
        float4 v = *(const float4*)(ib + (size_t)(c0 + c) * Tx + t0 + 4 * k);
        *(float4*)&lds[c][4 * k] = v;
    }
    __syncthreads();
    h16* xb = xT + (size_t)b * Tx * Cx;
#pragma unroll
    for (int i = 0; i < 4; i++) {
        int t = q + 16 * i;
        h16 o[4];
#pragma unroll
        for (int j = 0; j < 4; j++) o[j] = (h16)lds[4 * k + j][t];
        *(uint2*)(xb + (size_t)(t0 + t) * Cx + c0 + 4 * k) = *(uint2*)o;
    }
}

// ---------------------------------------------------------------------------
// out[b][c][t] = xT(f16 residual) + gamma[c]*(hT[b][t][c]-mu)*rsig + beta[c]
// BN finalize fused; residual from the f16 transposed copy (16 MB vs 64 MB
// fp32 re-read; error <= ~5e-4 abs). Work in [t][c] domain, transpose the
// finished sum through LDS, write out[c][t] coalesced.
// ---------------------------------------------------------------------------
__global__ __launch_bounds__(256)
void bn_apply_T(const h16* __restrict__ xT, const h16* __restrict__ hT,
                const float* __restrict__ psum, const float* __restrict__ pssq,
                const float* __restrict__ gamma, const float* __restrict__ beta,
                float* __restrict__ out) {
    __shared__ float lds[64][68];
    const int b = blockIdx.z, t0 = blockIdx.x * 64, c0 = blockIdx.y * 64;
    const int tid = threadIdx.x, q = tid >> 4, k = tid & 15;
    const float invN = 1.0f / (float)(Bx * Tx);
    // per-thread channel params for c = c0+4k .. c0+4k+3
    float mu[4], rv[4], ga[4], be[4];
#pragma unroll
    for (int j = 0; j < 4; j++) {
        int cg = c0 + 4 * k + j;
        float m = psum[cg] * invN;
        float var = pssq[cg] * invN - m * m;
        mu[j] = m;
        rv[j] = rsqrtf(var + EPSx);
        ga[j] = gamma[cg];
        be[j] = beta[cg];
    }
    const h16* hb = hT + (size_t)b * Tx * Cx;
    const h16* xb = xT + (size_t)b * Tx * Cx;
#pragma unroll
    for (int i = 0; i < 4; i++) {
        int t = q + 16 * i;
        size_t off = (size_t)(t0 + t) * Cx + c0 + 4 * k;
        uint2 hraw = *(const uint2*)(hb + off);
        uint2 xraw = *(const uint2*)(xb + off);
        const h16* hp = (const h16*)&hraw;
        const h16* xp = (const h16*)&xraw;
        float o[4];
#pragma unroll
        for (int j = 0; j < 4; j++)
            o[j] = (float)xp[j] + ga[j] * ((float)hp[j] - mu[j]) * rv[j] + be[j];
        *(float4*)&lds[t][4 * k] = *(float4*)o;
    }
    __syncthreads();
    float* ob = out + (size_t)b * Cx * Tx;
#pragma unroll
    for (int i = 0; i < 4; i++) {
        int c = q + 16 * i;
        int cg = c0 + c;
        float4 o;
        o.x = lds[4 * k + 0][c];
        o.y = lds[4 * k + 1][c];
        o.z = lds[4 * k + 2][c];
        o.w = lds[4 * k + 3][c];
        *(float4*)(ob + (size_t)cg * Tx + t0 + 4 * k) = o;
    }
}

// ---------------------------------------------------------------------------
// Pipeline (51.6 GF total):
//   1. prep:   xT = transpose(inpt) f16; weights->f16; zero Z/psum/pssq
//   2. proj:   thph[t][0:512) = xT . (theta|phi)^T + bias      (8.6 GF, DBUF)
//   3. logits: LT[s][t] = exp(phi[s].theta[t]); Z[t] += colsum (17.2 GF)
//   4. gT':    gT[d][t] = (g_w[d].xT[t] + g_b[d]) / Z[t] bf16  (4.3 GF, DBUF)
//   5. attn:   attn[s][d] = sum_t LT[s][t]*gT[d][t] f16        (17.2 GF, DBUF)
//   6. h:      hT[s][c] = attn[s].ht_w[c] + ht_b[c]; BN stats  (4.3 GF, DBUF)
//   7. bn_apply (residual from xT f16)
//
// Workspace (bytes, total ~130 MiB):
//   xT    @0             16,777,216  (f16 [b][t][c]; live to the end)
//   w4    @16,777,216     1,048,576  (theta|phi|g f16 768x512; wHt 512x256)
//   bias3 @17,825,792         3,072  (theta_b||phi_b||g_b)
//   Z     @17,828,864        65,536  (fp32 exp-row-sums [b][t])
//   psum  @17,894,400         2,048  (fp32 BN channel sums)
//   pssq  @17,896,448         2,048
//   thph  @17,902,592    16,777,216  (f16 [b][t][theta||phi], ld 512)
//   gT    @34,679,808     8,388,608  (bf16 [b][d][t] = g/Z, ld 2048)
//   attn  @43,068,416     8,388,608  (f16 [b][s][d], ld 256)
//   LT    @51,457,024    67,108,864  (bf16 exp-logits [b][s][t])
//   hT    @118,565,888   16,777,216  (f16 [b][t][c])
// ---------------------------------------------------------------------------
extern "C" void kernel_launch(void* const* d_in, const int* in_sizes, int n_in,
                              void* d_out, int out_size, void* d_ws, size_t ws_size,
                              hipStream_t stream) {
    const float* inpt    = (const float*)d_in[0];
    const float* theta_w = (const float*)d_in[1];
    const float* theta_b = (const float*)d_in[2];
    const float* phi_w   = (const float*)d_in[3];
    const float* phi_b   = (const float*)d_in[4];
    const float* g_w     = (const float*)d_in[5];
    const float* g_b     = (const float*)d_in[6];
    const float* ht_w    = (const float*)d_in[7];
    const float* ht_b    = (const float*)d_in[8];
    const float* gamma   = (const float*)d_in[9];
    const float* beta    = (const float*)d_in[10];

    char* ws = (char*)d_ws;
    h16*   xT    = (h16*)(ws + 0);
    h16*   w4    = (h16*)(ws + 16777216);     // theta|phi|g rows (768 x 512)
    h16*   wHt   = w4 + 393216;               // 512 rows x 256
    float* bias3 = (float*)(ws + 17825792);
    float* Z     = (float*)(ws + 17828864);
    float* psum  = (float*)(ws + 17894400);
    float* pssq  = (float*)(ws + 17896448);
    h16*   thph  = (h16*)(ws + 17902592);     // f16 [b][t][theta||phi] ld 512
    h16*   gT    = (h16*)(ws + 34679808);     // bf16 bits [b][d][t]
    h16*   attn  = (h16*)(ws + 43068416);     // f16 [b][s][d]
    h16*   LT    = (h16*)(ws + 51457024);     // bf16 bits [b][s][t]
    h16*   hT    = (h16*)(ws + 118565888);    // f16 [b][t][c]

    const long sX  = (long)Tx * Cx;    // 1,048,576 (xT, hT)
    const long sTP = (long)Tx * 512;   // 1,048,576 (thph)
    const long sGT = (long)Dx * Tx;    //   524,288 (gT)
    const long sAT = (long)Tx * Dx;    //   524,288 (attn)
    const long sW  = (long)Tx * Tx;    // 4,194,304 (LT)

    dim3 blk(256);
    // fused input transpose + weight conversion + zero-init
    conv_prep<<<dim3(Tx / 64, Cx / 64, Bx + 1), blk, 0, stream>>>(
        inpt, xT, theta_w, phi_w, g_w, ht_w, theta_b, phi_b, g_b,
        w4, bias3, Z, psum, pssq);
    // thph[t][n] = sum_c xT[t][c]*(theta||phi)[n][c] + bias3[n]   (f16)
    // grid: 8 batches x (16 m-blk x 4 n-blk) = 512 (2/CU -> DBUF)
    gemm_mf<0, false, 128, true><<<dim3(512), blk, 0, stream>>>(
        xT, sX, Cx, w4, 0, Cx, thph, sTP, 512, nullptr, nullptr,
        Tx, 512, Cx, 16, nullptr, bias3);
    // LT[s][t] = exp(sum_d phi[s][d]*theta[t][d]) bf16; Z[t] += col sums
    // grid: 8 x (16 x 16) = 2048 (8/CU of TLP -> keep single-buffered)
    gemm_mf<2, false, 128, false><<<dim3(2048), blk, 0, stream>>>(
        thph + 256, sTP, 512, thph, sTP, 512, LT, sW, Tx, nullptr, Z,
        Tx, Tx, Dx, 16, nullptr, nullptr);
    // gT[d][t] = (sum_c g_w[d][c]*xT[t][c] + g_b[d]) / Z[t]   (bf16)
    // grid: 8 x (2 m x 32 n) = 512 (2/CU -> DBUF)
    gemm_mf<1, false, 64, true><<<dim3(512), blk, 0, stream>>>(
        w4 + 512 * 512, 0, Cx, xT, sX, Cx, gT, sGT, Tx, nullptr, Z,
        Dx, Tx, Cx, 2, bias3 + 512, nullptr);
    // attn[s][d] = sum_t LT[s][t]*gT[d][t]   (bf16 in, f16 out)
    // grid: 8 x (16 m x 4 n) = 512 (2/CU, K=2048 -> DBUF)
    gemm_mf<0, true, 64, true><<<dim3(512), blk, 0, stream>>>(
        LT, sW, Tx, gT, sGT, Tx, attn, sAT, Dx, nullptr, nullptr,
        Tx, Dx, Tx, 16, nullptr, nullptr);
    // hT[s][c] = sum_d attn[s][d]*ht_w[c][d] + ht_b[c]; fused BN stat atomics
    // grid: 8 x (16 m x 8 n) = 1024 (short K -> DBUF)
    gemm_mf<3, false, 64, true><<<dim3(1024), blk, 0, stream>>>(
        attn, sAT, Dx, wHt, 0, Dx, hT, sX, Cx, psum, pssq,
        Tx, Cx, Dx, 16, nullptr, ht_b);
    bn_apply_T<<<dim3(Tx / 64, Cx / 64, Bx), blk, 0, stream>>>(
        xT, hT, psum, pssq, gamma, beta, (float*)d_out);
}

// Round 3
// 223.394 us; speedup vs baseline: 1.0348x; 1.0348x over previous
//
#include <hip/hip_runtime.h>
#include <hip/hip_bf16.h>
#include <math.h>

#define Bx 8
#define Cx 512
#define Dx 256
#define Tx 2048
#define EPSx 1e-5f

typedef _Float16 h16;
typedef __attribute__((ext_vector_type(8))) _Float16 h16x8;
typedef __attribute__((ext_vector_type(8))) short s16x8;
typedef __attribute__((ext_vector_type(4))) float f32x4;

typedef __attribute__((address_space(3))) unsigned int lds_u32;
typedef __attribute__((address_space(1))) const unsigned int glb_u32;

// async 16B global -> LDS DMA. ldsp must be wave-uniform; HW adds lane*16.
__device__ __forceinline__ void cp16(void* ldsp, const void* g) {
    __builtin_amdgcn_global_load_lds((glb_u32*)g, (lds_u32*)ldsp, 16, 0, 0);
}

// ---------------------------------------------------------------------------
// MFMA GEMM core: acc[m][n] = sum_k A[m][k]*B[n][k], 2-byte dtypes (f16/bf16),
// tile 128 x TN (TN=128 or 64), BK=64 (0-conflict LDS layout), 4 waves (2x2),
// global_load_lds staging with XOR swizzle. Single-buffered 2-barrier K-loop:
// explicit DBUF was tried (r2) and regressed +14us -- the inline vmcnt(0)
// "memory" asm pins compiler scheduling (m141 failure mode). Do not re-add.
// Grid: 1-D, batch->XCD swizzle: b = id & 7;
// rr = id >> 3; m0 = (rr % mBlk)*128; n0 = (rr / mBlk)*TN.
// Epilogue by MODE:
//   0: f16 out, + optional biasM[row] + biasN[col]                (projection)
//   1: bf16 out = (acc + optional biasM[row]) * (1/Z[b*N+col])    (gT' = g/Z)
//   2: bf16 out = exp(acc); atomicAdd Z[b*N+col] += col sums      (logits)
//   3: f16 out = acc + biasN[col]; atomicAdd Cp[col]+=sum(v),
//      Z[col]+=sum(v^2) (fused BatchNorm stats)                   (h GEMM)
// ---------------------------------------------------------------------------
template<int MODE, bool BF, int TN>
__global__ __launch_bounds__(256, 4)
void gemm_mf(const h16* __restrict__ A, long aBatch, int lda,
             const h16* __restrict__ B, long bBatch, int ldb,
             void* __restrict__ C, long cBatch, int ldc,
             float* __restrict__ Cp, float* __restrict__ Z,
             int M, int N, int K, int mBlk,
             const float* __restrict__ biasM, const float* __restrict__ biasN) {
    constexpr int NJ = TN / 32;          // B-frags per wave (n-dir)
    __shared__ h16 As[128 * 64];
    __shared__ h16 Bs[TN * 64];
    const int tid  = threadIdx.x;
    const int lane = tid & 63, wid = tid >> 6;
    const int wm = (wid & 1) * 64, wn = (wid >> 1) * (TN / 2);
    const int lm = lane & 15, quad = lane >> 4;
    const unsigned id = blockIdx.x;
    const int b = id & 7;
    const unsigned rr = id >> 3;
    const int m0 = (rr % (unsigned)mBlk) * 128;
    const int n0 = (rr / (unsigned)mBlk) * TN;
    const h16* Ab = A + (size_t)b * aBatch + (size_t)m0 * lda;
    const h16* Bb = B + (size_t)b * bBatch + (size_t)n0 * ldb;

    const int srow  = tid >> 3;                 // row within 32-row group
    const int sclog = (tid & 7) ^ (srow & 7);   // logical k-chunk (XOR swizzle)
    char* ldsA = (char*)As + (tid & ~63) * 16;  // wave-uniform base
    char* ldsB = (char*)Bs + (tid & ~63) * 16;

    f32x4 acc[4][NJ] = {};

    for (int k0 = 0; k0 < K; k0 += 64) {
        __syncthreads();   // all waves done reading previous tile
#pragma unroll
        for (int i = 0; i < 4; i++) {
            int r = srow + 32 * i;
            cp16(ldsA + i * 4096, Ab + (size_t)r * lda + k0 + sclog * 8);
        }
#pragma unroll
        for (int i = 0; i < TN / 32; i++) {
            int r = srow + 32 * i;
            cp16(ldsB + i * 4096, Bb + (size_t)r * ldb + k0 + sclog * 8);
        }
        __syncthreads();   // drains vmcnt(0): tile resident
#pragma unroll
        for (int ks = 0; ks < 2; ks++) {
            s16x8 af[4], bf4[NJ];
#pragma unroll
            for (int i = 0; i < 4; i++) {
                int row = wm + 16 * i + lm;
                int st = (ks * 4 + quad) ^ (lm & 7);
                af[i] = *(const s16x8*)(As + row * 64 + st * 8);
            }
#pragma unroll
            for (int j = 0; j < NJ; j++) {
                int row = wn + 16 * j + lm;
                int st = (ks * 4 + quad) ^ (lm & 7);
                bf4[j] = *(const s16x8*)(Bs + row * 64 + st * 8);
            }
#pragma unroll
            for (int i = 0; i < 4; i++)
#pragma unroll
                for (int j = 0; j < NJ; j++) {
                    if constexpr (BF)
                        acc[i][j] = __builtin_amdgcn_mfma_f32_16x16x32_bf16(
                            af[i], bf4[j], acc[i][j], 0, 0, 0);
                    else
                        acc[i][j] = __builtin_amdgcn_mfma_f32_16x16x32_f16(
                            __builtin_bit_cast(h16x8, af[i]),
                            __builtin_bit_cast(h16x8, bf4[j]), acc[i][j], 0, 0, 0);
                }
        }
    }

    // epilogue: C/D layout col=lane&15, row=quad*4+reg
    if constexpr (MODE == 0) {
        h16* Cb = (h16*)C + (size_t)b * cBatch;
#pragma unroll
        for (int i = 0; i < 4; i++)
#pragma unroll
            for (int j = 0; j < NJ; j++) {
                int row = m0 + wm + 16 * i + quad * 4;
                int col = n0 + wn + 16 * j + lm;
                float bN = biasN ? biasN[col] : 0.0f;
#pragma unroll
                for (int r = 0; r < 4; r++) {
                    float v = acc[i][j][r] + bN;
                    if (biasM) v += biasM[row + r];
                    Cb[(size_t)(row + r) * ldc + col] = (h16)v;
                }
            }
    } else if constexpr (MODE == 1) {
        __hip_bfloat16* Cb = (__hip_bfloat16*)C + (size_t)b * cBatch;
#pragma unroll
        for (int j = 0; j < NJ; j++) {
            int col = n0 + wn + 16 * j + lm;
            float iz = 1.0f / Z[(size_t)b * N + col];
#pragma unroll
            for (int i = 0; i < 4; i++) {
                int row = m0 + wm + 16 * i + quad * 4;
#pragma unroll
                for (int r = 0; r < 4; r++) {
                    float v = acc[i][j][r];
                    if (biasM) v += biasM[row + r];
                    Cb[(size_t)(row + r) * ldc + col] = __float2bfloat16(v * iz);
                }
            }
        }
    } else if constexpr (MODE == 2) {
        __syncthreads();                       // fragments consumed
        float* Zl = (float*)As;
        if (tid < TN) Zl[tid] = 0.0f;
        __syncthreads();
        __hip_bfloat16* Cb = (__hip_bfloat16*)C + (size_t)b * cBatch;
#pragma unroll
        for (int j = 0; j < NJ; j++) {
            int cl = wn + 16 * j + lm;
            int col = n0 + cl;
            float zp = 0.0f;
#pragma unroll
            for (int i = 0; i < 4; i++) {
                int row = m0 + wm + 16 * i + quad * 4;
#pragma unroll
                for (int r = 0; r < 4; r++) {
                    float e = __expf(acc[i][j][r]);
                    zp += e;
                    Cb[(size_t)(row + r) * ldc + col] = __float2bfloat16(e);
                }
            }
            atomicAdd(&Zl[cl], zp);
        }
        __syncthreads();
        if (tid < TN) atomicAdd(&Z[(size_t)b * N + n0 + tid], Zl[tid]);
    } else {  // MODE 3: f16 out + biasN, fused BN sum/sumsq atomics
        __syncthreads();                       // fragments consumed
        float* Sl = (float*)As;                // [0:TN) col sums
        float* Sq = Sl + TN;                   // [TN:2TN) col sumsq
        if (tid < 2 * TN) Sl[tid] = 0.0f;
        __syncthreads();
        h16* Cb = (h16*)C + (size_t)b * cBatch;
#pragma unroll
        for (int j = 0; j < NJ; j++) {
            int cl = wn + 16 * j + lm;
            int col = n0 + cl;
            float bN = biasN[col];
            float s = 0.0f, q = 0.0f;
#pragma unroll
            for (int i = 0; i < 4; i++) {
                int row = m0 + wm + 16 * i + quad * 4;
#pragma unroll
                for (int r = 0; r < 4; r++) {
                    float v = acc[i][j][r] + bN;
                    s += v;
                    q = fmaf(v, v, q);
                    Cb[(size_t)(row + r) * ldc + col] = (h16)v;
                }
            }
            atomicAdd(&Sl[cl], s);
            atomicAdd(&Sq[cl], q);
        }
        __syncthreads();
        if (tid < TN) {
            atomicAdd(&Cp[n0 + tid], Sl[tid]);
            atomicAdd(&Z[n0 + tid], Sq[tid]);
        }
    }
}

// ---------------------------------------------------------------------------
// Fused prep: z<8  -> inpt[b][c][t] fp32 -> xT[b][t][c] f16 (64x64 transpose)
//             z==8 -> weights->f16 concat, bias3, Z/psum/pssq zero-init.
// ---------------------------------------------------------------------------
__global__ __launch_bounds__(256)
void conv_prep(const float* __restrict__ inpt, h16* __restrict__ xT,
               const float* __restrict__ w0, const float* __restrict__ w1,
               const float* __restrict__ w2, const float* __restrict__ w3,
               const float* __restrict__ tb, const float* __restrict__ pb,
               const float* __restrict__ gb,
               h16* __restrict__ dst, float* __restrict__ bias3,
               float* __restrict__ Z, float* __restrict__ psum,
               float* __restrict__ pssq) {
    const int tid = threadIdx.x;
    if (blockIdx.z == 8) {
        int bx = blockIdx.y * 32 + blockIdx.x;          // 0..255
        // weights: 131072 float4 total, 512 per block
#pragma unroll
        for (int rep = 0; rep < 2; rep++) {
            int idx4 = bx * 512 + rep * 256 + tid;
            int arr = idx4 >> 15, local4 = idx4 & 32767;
            const float* srcs[4] = {w0, w1, w2, w3};
            float4 v = ((const float4*)srcs[arr])[local4];
            h16 o[4] = {(h16)v.x, (h16)v.y, (h16)v.z, (h16)v.w};
            *(uint2*)(dst + (size_t)arr * 131072 + (size_t)local4 * 4) = *(uint2*)o;
        }
        if (bx < 64) Z[bx * 256 + tid] = 0.0f;          // 16384 floats
        if (bx == 64) bias3[tid] = tb[tid];
        if (bx == 65) bias3[256 + tid] = pb[tid];
        if (bx == 66) bias3[512 + tid] = gb[tid];
        if (bx == 67) {
            psum[tid] = 0.0f; psum[tid + 256] = 0.0f;
            pssq[tid] = 0.0f; pssq[tid + 256] = 0.0f;
        }
        return;
    }
    __shared__ float lds[64][68];
    const int b = blockIdx.z;
    const int t0 = blockIdx.x * 64, c0 = blockIdx.y * 64;
    const int q = tid >> 4, k = tid & 15;
    const float* ib = inpt + (size_t)b * Cx * Tx;
#pragma unroll
    for (int i = 0; i < 4; i++) {
        int c = q + 16 * i;
        float4 v = *(const float4*)(ib + (size_t)(c0 + c) * Tx + t0 + 4 * k);
        *(float4*)&lds[c][4 * k] = v;
    }
    __syncthreads();
    h16* xb = xT + (size_t)b * Tx * Cx;
#pragma unroll
    for (int i = 0; i < 4; i++) {
        int t = q + 16 * i;
        h16 o[4];
#pragma unroll
        for (int j = 0; j < 4; j++) o[j] = (h16)lds[4 * k + j][t];
        *(uint2*)(xb + (size_t)(t0 + t) * Cx + c0 + 4 * k) = *(uint2*)o;
    }
}

// ---------------------------------------------------------------------------
// out[b][c][t] = xT(f16 residual) + gamma[c]*(hT[b][t][c]-mu)*rsig + beta[c]
// BN finalize fused; residual from the f16 transposed copy (16 MB vs 64 MB
// fp32 re-read; error <= ~5e-4 abs, verified r2 absmax unchanged). Work in
// [t][c] domain, transpose finished sum through LDS, write out[c][t] coalesced.
// ---------------------------------------------------------------------------
__global__ __launch_bounds__(256)
void bn_apply_T(const h16* __restrict__ xT, const h16* __restrict__ hT,
                const float* __restrict__ psum, const float* __restrict__ pssq,
                const float* __restrict__ gamma, const float* __restrict__ beta,
                float* __restrict__ out) {
    __shared__ float lds[64][68];
    const int b = blockIdx.z, t0 = blockIdx.x * 64, c0 = blockIdx.y * 64;
    const int tid = threadIdx.x, q = tid >> 4, k = tid & 15;
    const float invN = 1.0f / (float)(Bx * Tx);
    // per-thread channel params for c = c0+4k .. c0+4k+3
    float mu[4], rv[4], ga[4], be[4];
#pragma unroll
    for (int j = 0; j < 4; j++) {
        int cg = c0 + 4 * k + j;
        float m = psum[cg] * invN;
        float var = pssq[cg] * invN - m * m;
        mu[j] = m;
        rv[j] = rsqrtf(var + EPSx);
        ga[j] = gamma[cg];
        be[j] = beta[cg];
    }
    const h16* hb = hT + (size_t)b * Tx * Cx;
    const h16* xb = xT + (size_t)b * Tx * Cx;
#pragma unroll
    for (int i = 0; i < 4; i++) {
        int t = q + 16 * i;
        size_t off = (size_t)(t0 + t) * Cx + c0 + 4 * k;
        uint2 hraw = *(const uint2*)(hb + off);
        uint2 xraw = *(const uint2*)(xb + off);
        const h16* hp = (const h16*)&hraw;
        const h16* xp = (const h16*)&xraw;
        float o[4];
#pragma unroll
        for (int j = 0; j < 4; j++)
            o[j] = (float)xp[j] + ga[j] * ((float)hp[j] - mu[j]) * rv[j] + be[j];
        *(float4*)&lds[t][4 * k] = *(float4*)o;
    }
    __syncthreads();
    float* ob = out + (size_t)b * Cx * Tx;
#pragma unroll
    for (int i = 0; i < 4; i++) {
        int c = q + 16 * i;
        int cg = c0 + c;
        float4 o;
        o.x = lds[4 * k + 0][c];
        o.y = lds[4 * k + 1][c];
        o.z = lds[4 * k + 2][c];
        o.w = lds[4 * k + 3][c];
        *(float4*)(ob + (size_t)cg * Tx + t0 + 4 * k) = o;
    }
}

// ---------------------------------------------------------------------------
// Pipeline (51.6 GF total):
//   1. prep:   xT = transpose(inpt) f16; weights->f16; zero Z/psum/pssq
//   2. proj:   thph[t][0:512) = xT . (theta|phi)^T + bias      (8.6 GF)
//   3. logits: LT[s][t] = exp(phi[s].theta[t]); Z[t] += colsum (17.2 GF)
//   4. gT':    gT[d][t] = (g_w[d].xT[t] + g_b[d]) / Z[t] bf16  (4.3 GF)
//   5. attn:   attn[s][d] = sum_t LT[s][t]*gT[d][t] f16        (17.2 GF)
//   6. h:      hT[s][c] = attn[s].ht_w[c] + ht_b[c]; BN stats  (4.3 GF)
//   7. bn_apply (residual from xT f16)
//
// Workspace (bytes, total ~130 MiB):
//   xT    @0             16,777,216  (f16 [b][t][c]; live to the end)
//   w4    @16,777,216     1,048,576  (theta|phi|g f16 768x512; wHt 512x256)
//   bias3 @17,825,792         3,072  (theta_b||phi_b||g_b)
//   Z     @17,828,864        65,536  (fp32 exp-row-sums [b][t])
//   psum  @17,894,400         2,048  (fp32 BN channel sums)
//   pssq  @17,896,448         2,048
//   thph  @17,902,592    16,777,216  (f16 [b][t][theta||phi], ld 512)
//   gT    @34,679,808     8,388,608  (bf16 [b][d][t] = g/Z, ld 2048)
//   attn  @43,068,416     8,388,608  (f16 [b][s][d], ld 256)
//   LT    @51,457,024    67,108,864  (bf16 exp-logits [b][s][t])
//   hT    @118,565,888   16,777,216  (f16 [b][t][c])
// ---------------------------------------------------------------------------
extern "C" void kernel_launch(void* const* d_in, const int* in_sizes, int n_in,
                              void* d_out, int out_size, void* d_ws, size_t ws_size,
                              hipStream_t stream) {
    const float* inpt    = (const float*)d_in[0];
    const float* theta_w = (const float*)d_in[1];
    const float* theta_b = (const float*)d_in[2];
    const float* phi_w   = (const float*)d_in[3];
    const float* phi_b   = (const float*)d_in[4];
    const float* g_w     = (const float*)d_in[5];
    const float* g_b     = (const float*)d_in[6];
    const float* ht_w    = (const float*)d_in[7];
    const float* ht_b    = (const float*)d_in[8];
    const float* gamma   = (const float*)d_in[9];
    const float* beta    = (const float*)d_in[10];

    char* ws = (char*)d_ws;
    h16*   xT    = (h16*)(ws + 0);
    h16*   w4    = (h16*)(ws + 16777216);     // theta|phi|g rows (768 x 512)
    h16*   wHt   = w4 + 393216;               // 512 rows x 256
    float* bias3 = (float*)(ws + 17825792);
    float* Z     = (float*)(ws + 17828864);
    float* psum  = (float*)(ws + 17894400);
    float* pssq  = (float*)(ws + 17896448);
    h16*   thph  = (h16*)(ws + 17902592);     // f16 [b][t][theta||phi] ld 512
    h16*   gT    = (h16*)(ws + 34679808);     // bf16 bits [b][d][t]
    h16*   attn  = (h16*)(ws + 43068416);     // f16 [b][s][d]
    h16*   LT    = (h16*)(ws + 51457024);     // bf16 bits [b][s][t]
    h16*   hT    = (h16*)(ws + 118565888);    // f16 [b][t][c]

    const long sX  = (long)Tx * Cx;    // 1,048,576 (xT, hT)
    const long sTP = (long)Tx * 512;   // 1,048,576 (thph)
    const long sGT = (long)Dx * Tx;    //   524,288 (gT)
    const long sAT = (long)Tx * Dx;    //   524,288 (attn)
    const long sW  = (long)Tx * Tx;    // 4,194,304 (LT)

    dim3 blk(256);
    // fused input transpose + weight conversion + zero-init
    conv_prep<<<dim3(Tx / 64, Cx / 64, Bx + 1), blk, 0, stream>>>(
        inpt, xT, theta_w, phi_w, g_w, ht_w, theta_b, phi_b, g_b,
        w4, bias3, Z, psum, pssq);
    // thph[t][n] = sum_c xT[t][c]*(theta||phi)[n][c] + bias3[n]   (f16)
    // grid: 8 batches x (16 m-blk x 4 n-blk) = 512
    gemm_mf<0, false, 128><<<dim3(512), blk, 0, stream>>>(
        xT, sX, Cx, w4, 0, Cx, thph, sTP, 512, nullptr, nullptr,
        Tx, 512, Cx, 16, nullptr, bias3);
    // LT[s][t] = exp(sum_d phi[s][d]*theta[t][d]) bf16; Z[t] += col sums
    // grid: 8 x (16 x 16) = 2048
    gemm_mf<2, false, 128><<<dim3(2048), blk, 0, stream>>>(
        thph + 256, sTP, 512, thph, sTP, 512, LT, sW, Tx, nullptr, Z,
        Tx, Tx, Dx, 16, nullptr, nullptr);
    // gT[d][t] = (sum_c g_w[d][c]*xT[t][c] + g_b[d]) / Z[t]   (bf16)
    // grid: 8 x (2 m x 32 n) = 512
    gemm_mf<1, false, 64><<<dim3(512), blk, 0, stream>>>(
        w4 + 512 * 512, 0, Cx, xT, sX, Cx, gT, sGT, Tx, nullptr, Z,
        Dx, Tx, Cx, 2, bias3 + 512, nullptr);
    // attn[s][d] = sum_t LT[s][t]*gT[d][t]   (bf16 in, f16 out)
    // grid: 8 x (16 m x 4 n) = 512
    gemm_mf<0, true, 64><<<dim3(512), blk, 0, stream>>>(
        LT, sW, Tx, gT, sGT, Tx, attn, sAT, Dx, nullptr, nullptr,
        Tx, Dx, Tx, 16, nullptr, nullptr);
    // hT[s][c] = sum_d attn[s][d]*ht_w[c][d] + ht_b[c]; fused BN stat atomics
    // grid: 8 x (16 m x 8 n) = 1024
    gemm_mf<3, false, 64><<<dim3(1024), blk, 0, stream>>>(
        attn, sAT, Dx, wHt, 0, Dx, hT, sX, Cx, psum, pssq,
        Tx, Cx, Dx, 16, nullptr, ht_b);
    bn_apply_T<<<dim3(Tx / 64, Cx / 64, Bx), blk, 0, stream>>>(
        xT, hT, psum, pssq, gamma, beta, (float*)d_out);
}

// Round 4
// 207.509 us; speedup vs baseline: 1.1141x; 1.0766x over previous
//
#include <hip/hip_runtime.h>
#include <hip/hip_bf16.h>
#include <math.h>

#define Bx 8
#define Cx 512
#define Dx 256
#define Tx 2048
#define EPSx 1e-5f

typedef _Float16 h16;
typedef __attribute__((ext_vector_type(8))) _Float16 h16x8;
typedef __attribute__((ext_vector_type(8))) short s16x8;
typedef __attribute__((ext_vector_type(4))) float f32x4;

typedef __attribute__((address_space(3))) unsigned int lds_u32;
typedef __attribute__((address_space(1))) const unsigned int glb_u32;

// async 16B global -> LDS DMA. ldsp must be wave-uniform; HW adds lane*16.
__device__ __forceinline__ void cp16(void* ldsp, const void* g) {
    __builtin_amdgcn_global_load_lds((glb_u32*)g, (lds_u32*)ldsp, 16, 0, 0);
}

// ---------------------------------------------------------------------------
// MFMA GEMM core: acc[m][n] = sum_k A[m][k]*B[n][k], 2-byte dtypes (f16/bf16),
// tile TM x TN (TM in {128,64}), BK=64 (0-conflict LDS layout), 4 waves,
// global_load_lds staging with XOR swizzle. Single-buffered 2-barrier K-loop:
// explicit DBUF was tried (r2) and regressed +14us (m141 order-pinning
// failure mode). Do not re-add.
// Wave layout: TM=128 -> 2x2 waves (wm=(wid&1)*64, wn=(wid>>1)*TN/2);
//              TM=64  -> 1x4 waves (wm=0, wn=wid*TN/4). Smaller tile buys
//              grid TLP (4 blocks/CU) for skinny N -- r4 change.
// Grid: 1-D, batch->XCD swizzle: b = id & 7;
// rr = id >> 3; m0 = (rr % mBlk)*TM; n0 = (rr / mBlk)*TN.
// Epilogue by MODE:
//   0: f16 out, + optional biasM[row] + biasN[col]                (projection)
//   1: bf16 out = (acc + optional biasM[row]) * (1/Z[b*N+col])    (gT' = g/Z)
//   2: bf16 out = exp(acc); atomicAdd Z[b*N+col] += col sums      (logits)
//   3: f16 out = acc + biasN[col]; atomicAdd Cp[col]+=sum(v),
//      Z[col]+=sum(v^2) (fused BatchNorm stats)                   (h GEMM)
// ---------------------------------------------------------------------------
template<int MODE, bool BF, int TM, int TN>
__global__ __launch_bounds__(256, 4)
void gemm_mf(const h16* __restrict__ A, long aBatch, int lda,
             const h16* __restrict__ B, long bBatch, int ldb,
             void* __restrict__ C, long cBatch, int ldc,
             float* __restrict__ Cp, float* __restrict__ Z,
             int M, int N, int K, int mBlk,
             const float* __restrict__ biasM, const float* __restrict__ biasN) {
    constexpr int WN = (TM == 128) ? TN / 2 : TN / 4;  // per-wave n-width
    constexpr int NJ = WN / 16;                        // B-frags per wave
    __shared__ h16 As[TM * 64];
    __shared__ h16 Bs[TN * 64];
    const int tid  = threadIdx.x;
    const int lane = tid & 63, wid = tid >> 6;
    const int wm = (TM == 128) ? (wid & 1) * 64 : 0;
    const int wn = (TM == 128) ? (wid >> 1) * WN : wid * WN;
    const int lm = lane & 15, quad = lane >> 4;
    const unsigned id = blockIdx.x;
    const int b = id & 7;
    const unsigned rr = id >> 3;
    const int m0 = (rr % (unsigned)mBlk) * TM;
    const int n0 = (rr / (unsigned)mBlk) * TN;
    const h16* Ab = A + (size_t)b * aBatch + (size_t)m0 * lda;
    const h16* Bb = B + (size_t)b * bBatch + (size_t)n0 * ldb;

    const int srow  = tid >> 3;                 // row within 32-row group
    const int sclog = (tid & 7) ^ (srow & 7);   // logical k-chunk (XOR swizzle)
    char* ldsA = (char*)As + (tid & ~63) * 16;  // wave-uniform base
    char* ldsB = (char*)Bs + (tid & ~63) * 16;

    f32x4 acc[4][NJ] = {};

    for (int k0 = 0; k0 < K; k0 += 64) {
        __syncthreads();   // all waves done reading previous tile
#pragma unroll
        for (int i = 0; i < TM / 32; i++) {
            int r = srow + 32 * i;
            cp16(ldsA + i * 4096, Ab + (size_t)r * lda + k0 + sclog * 8);
        }
#pragma unroll
        for (int i = 0; i < TN / 32; i++) {
            int r = srow + 32 * i;
            cp16(ldsB + i * 4096, Bb + (size_t)r * ldb + k0 + sclog * 8);
        }
        __syncthreads();   // drains vmcnt(0): tile resident
#pragma unroll
        for (int ks = 0; ks < 2; ks++) {
            s16x8 af[4], bf4[NJ];
#pragma unroll
            for (int i = 0; i < 4; i++) {
                int row = wm + 16 * i + lm;
                int st = (ks * 4 + quad) ^ (lm & 7);
                af[i] = *(const s16x8*)(As + row * 64 + st * 8);
            }
#pragma unroll
            for (int j = 0; j < NJ; j++) {
                int row = wn + 16 * j + lm;
                int st = (ks * 4 + quad) ^ (lm & 7);
                bf4[j] = *(const s16x8*)(Bs + row * 64 + st * 8);
            }
#pragma unroll
            for (int i = 0; i < 4; i++)
#pragma unroll
                for (int j = 0; j < NJ; j++) {
                    if constexpr (BF)
                        acc[i][j] = __builtin_amdgcn_mfma_f32_16x16x32_bf16(
                            af[i], bf4[j], acc[i][j], 0, 0, 0);
                    else
                        acc[i][j] = __builtin_amdgcn_mfma_f32_16x16x32_f16(
                            __builtin_bit_cast(h16x8, af[i]),
                            __builtin_bit_cast(h16x8, bf4[j]), acc[i][j], 0, 0, 0);
                }
        }
    }

    // epilogue: C/D layout col=lane&15, row=quad*4+reg
    if constexpr (MODE == 0) {
        h16* Cb = (h16*)C + (size_t)b * cBatch;
#pragma unroll
        for (int i = 0; i < 4; i++)
#pragma unroll
            for (int j = 0; j < NJ; j++) {
                int row = m0 + wm + 16 * i + quad * 4;
                int col = n0 + wn + 16 * j + lm;
                float bN = biasN ? biasN[col] : 0.0f;
#pragma unroll
                for (int r = 0; r < 4; r++) {
                    float v = acc[i][j][r] + bN;
                    if (biasM) v += biasM[row + r];
                    Cb[(size_t)(row + r) * ldc + col] = (h16)v;
                }
            }
    } else if constexpr (MODE == 1) {
        __hip_bfloat16* Cb = (__hip_bfloat16*)C + (size_t)b * cBatch;
#pragma unroll
        for (int j = 0; j < NJ; j++) {
            int col = n0 + wn + 16 * j + lm;
            float iz = 1.0f / Z[(size_t)b * N + col];
#pragma unroll
            for (int i = 0; i < 4; i++) {
                int row = m0 + wm + 16 * i + quad * 4;
#pragma unroll
                for (int r = 0; r < 4; r++) {
                    float v = acc[i][j][r];
                    if (biasM) v += biasM[row + r];
                    Cb[(size_t)(row + r) * ldc + col] = __float2bfloat16(v * iz);
                }
            }
        }
    } else if constexpr (MODE == 2) {
        __syncthreads();                       // fragments consumed
        float* Zl = (float*)As;
        if (tid < TN) Zl[tid] = 0.0f;
        __syncthreads();
        __hip_bfloat16* Cb = (__hip_bfloat16*)C + (size_t)b * cBatch;
#pragma unroll
        for (int j = 0; j < NJ; j++) {
            int cl = wn + 16 * j + lm;
            int col = n0 + cl;
            float zp = 0.0f;
#pragma unroll
            for (int i = 0; i < 4; i++) {
                int row = m0 + wm + 16 * i + quad * 4;
#pragma unroll
                for (int r = 0; r < 4; r++) {
                    float e = __expf(acc[i][j][r]);
                    zp += e;
                    Cb[(size_t)(row + r) * ldc + col] = __float2bfloat16(e);
                }
            }
            atomicAdd(&Zl[cl], zp);
        }
        __syncthreads();
        if (tid < TN) atomicAdd(&Z[(size_t)b * N + n0 + tid], Zl[tid]);
    } else {  // MODE 3: f16 out + biasN, fused BN sum/sumsq atomics
        __syncthreads();                       // fragments consumed
        float* Sl = (float*)As;                // [0:TN) col sums
        float* Sq = Sl + TN;                   // [TN:2TN) col sumsq
        if (tid < 2 * TN) Sl[tid] = 0.0f;
        __syncthreads();
        h16* Cb = (h16*)C + (size_t)b * cBatch;
#pragma unroll
        for (int j = 0; j < NJ; j++) {
            int cl = wn + 16 * j + lm;
            int col = n0 + cl;
            float bN = biasN[col];
            float s = 0.0f, q = 0.0f;
#pragma unroll
            for (int i = 0; i < 4; i++) {
                int row = m0 + wm + 16 * i + quad * 4;
#pragma unroll
                for (int r = 0; r < 4; r++) {
                    float v = acc[i][j][r] + bN;
                    s += v;
                    q = fmaf(v, v, q);
                    Cb[(size_t)(row + r) * ldc + col] = (h16)v;
                }
            }
            atomicAdd(&Sl[cl], s);
            atomicAdd(&Sq[cl], q);
        }
        __syncthreads();
        if (tid < TN) {
            atomicAdd(&Cp[n0 + tid], Sl[tid]);
            atomicAdd(&Z[n0 + tid], Sq[tid]);
        }
    }
}

// ---------------------------------------------------------------------------
// Fused prep: z<8  -> inpt[b][c][t] fp32 -> xT[b][t][c] f16 (64x64 transpose)
//             z==8 -> weights->f16 concat, bias3, Z/psum/pssq zero-init.
// ---------------------------------------------------------------------------
__global__ __launch_bounds__(256)
void conv_prep(const float* __restrict__ inpt, h16* __restrict__ xT,
               const float* __restrict__ w0, const float* __restrict__ w1,
               const float* __restrict__ w2, const float* __restrict__ w3,
               const float* __restrict__ tb, const float* __restrict__ pb,
               const float* __restrict__ gb,
               h16* __restrict__ dst, float* __restrict__ bias3,
               float* __restrict__ Z, float* __restrict__ psum,
               float* __restrict__ pssq) {
    const int tid = threadIdx.x;
    if (blockIdx.z == 8) {
        int bx = blockIdx.y * 32 + blockIdx.x;          // 0..255
        // weights: 131072 float4 total, 512 per block
#pragma unroll
        for (int rep = 0; rep < 2; rep++) {
            int idx4 = bx * 512 + rep * 256 + tid;
            int arr = idx4 >> 15, local4 = idx4 & 32767;
            const float* srcs[4] = {w0, w1, w2, w3};
            float4 v = ((const float4*)srcs[arr])[local4];
            h16 o[4] = {(h16)v.x, (h16)v.y, (h16)v.z, (h16)v.w};
            *(uint2*)(dst + (size_t)arr * 131072 + (size_t)local4 * 4) = *(uint2*)o;
        }
        if (bx < 64) Z[bx * 256 + tid] = 0.0f;          // 16384 floats
        if (bx == 64) bias3[tid] = tb[tid];
        if (bx == 65) bias3[256 + tid] = pb[tid];
        if (bx == 66) bias3[512 + tid] = gb[tid];
        if (bx == 67) {
            psum[tid] = 0.0f; psum[tid + 256] = 0.0f;
            pssq[tid] = 0.0f; pssq[tid + 256] = 0.0f;
        }
        return;
    }
    __shared__ float lds[64][68];
    const int b = blockIdx.z;
    const int t0 = blockIdx.x * 64, c0 = blockIdx.y * 64;
    const int q = tid >> 4, k = tid & 15;
    const float* ib = inpt + (size_t)b * Cx * Tx;
#pragma unroll
    for (int i = 0; i < 4; i++) {
        int c = q + 16 * i;
        float4 v = *(const float4*)(ib + (size_t)(c0 + c) * Tx + t0 + 4 * k);
        *(float4*)&lds[c][4 * k] = v;
    }
    __syncthreads();
    h16* xb = xT + (size_t)b * Tx * Cx;
#pragma unroll
    for (int i = 0; i < 4; i++) {
        int t = q + 16 * i;
        h16 o[4];
#pragma unroll
        for (int j = 0; j < 4; j++) o[j] = (h16)lds[4 * k + j][t];
        *(uint2*)(xb + (size_t)(t0 + t) * Cx + c0 + 4 * k) = *(uint2*)o;
    }
}

// ---------------------------------------------------------------------------
// out[b][c][t] = xT(f16 residual) + gamma[c]*(hT[b][t][c]-mu)*rsig + beta[c]
// BN finalize fused; residual from the f16 transposed copy (16 MB vs 64 MB
// fp32 re-read; verified r2/r3 absmax unchanged). Work in [t][c] domain,
// transpose finished sum through LDS, write out[c][t] coalesced.
// ---------------------------------------------------------------------------
__global__ __launch_bounds__(256)
void bn_apply_T(const h16* __restrict__ xT, const h16* __restrict__ hT,
                const float* __restrict__ psum, const float* __restrict__ pssq,
                const float* __restrict__ gamma, const float* __restrict__ beta,
                float* __restrict__ out) {
    __shared__ float lds[64][68];
    const int b = blockIdx.z, t0 = blockIdx.x * 64, c0 = blockIdx.y * 64;
    const int tid = threadIdx.x, q = tid >> 4, k = tid & 15;
    const float invN = 1.0f / (float)(Bx * Tx);
    // per-thread channel params for c = c0+4k .. c0+4k+3
    float mu[4], rv[4], ga[4], be[4];
#pragma unroll
    for (int j = 0; j < 4; j++) {
        int cg = c0 + 4 * k + j;
        float m = psum[cg] * invN;
        float var = pssq[cg] * invN - m * m;
        mu[j] = m;
        rv[j] = rsqrtf(var + EPSx);
        ga[j] = gamma[cg];
        be[j] = beta[cg];
    }
    const h16* hb = hT + (size_t)b * Tx * Cx;
    const h16* xb = xT + (size_t)b * Tx * Cx;
#pragma unroll
    for (int i = 0; i < 4; i++) {
        int t = q + 16 * i;
        size_t off = (size_t)(t0 + t) * Cx + c0 + 4 * k;
        uint2 hraw = *(const uint2*)(hb + off);
        uint2 xraw = *(const uint2*)(xb + off);
        const h16* hp = (const h16*)&hraw;
        const h16* xp = (const h16*)&xraw;
        float o[4];
#pragma unroll
        for (int j = 0; j < 4; j++)
            o[j] = (float)xp[j] + ga[j] * ((float)hp[j] - mu[j]) * rv[j] + be[j];
        *(float4*)&lds[t][4 * k] = *(float4*)o;
    }
    __syncthreads();
    float* ob = out + (size_t)b * Cx * Tx;
#pragma unroll
    for (int i = 0; i < 4; i++) {
        int c = q + 16 * i;
        int cg = c0 + c;
        float4 o;
        o.x = lds[4 * k + 0][c];
        o.y = lds[4 * k + 1][c];
        o.z = lds[4 * k + 2][c];
        o.w = lds[4 * k + 3][c];
        *(float4*)(ob + (size_t)cg * Tx + t0 + 4 * k) = o;
    }
}

// ---------------------------------------------------------------------------
// Pipeline (51.6 GF total), all GEMMs at >=4 blocks/CU (r4 TLP change):
//   1. prep:   xT = transpose(inpt) f16; weights->f16; zero Z/psum/pssq
//   2. proj:   thph[t][0:512) = xT.(theta|phi)^T + bias   (8.6 GF, 128x64)
//   3. logits: LT[s][t]=exp(phi[s].theta[t]); Z[t]+=csum  (17.2 GF, 128x128)
//   4. gT':    gT[d][t]=(g_w[d].xT[t]+g_b[d])/Z[t] bf16   (4.3 GF, 64x64)
//   5. attn:   attn[s][d]=sum_t LT[s][t]*gT[d][t] f16     (17.2 GF, 64x64)
//   6. h:      hT[s][c]=attn[s].ht_w[c]+ht_b[c]; BN stats (4.3 GF, 128x64)
//   7. bn_apply (residual from xT f16)
//
// Workspace (bytes, total ~130 MiB):
//   xT    @0             16,777,216  (f16 [b][t][c]; live to the end)
//   w4    @16,777,216     1,048,576  (theta|phi|g f16 768x512; wHt 512x256)
//   bias3 @17,825,792         3,072  (theta_b||phi_b||g_b)
//   Z     @17,828,864        65,536  (fp32 exp-row-sums [b][t])
//   psum  @17,894,400         2,048  (fp32 BN channel sums)
//   pssq  @17,896,448         2,048
//   thph  @17,902,592    16,777,216  (f16 [b][t][theta||phi], ld 512)
//   gT    @34,679,808     8,388,608  (bf16 [b][d][t] = g/Z, ld 2048)
//   attn  @43,068,416     8,388,608  (f16 [b][s][d], ld 256)
//   LT    @51,457,024    67,108,864  (bf16 exp-logits [b][s][t])
//   hT    @118,565,888   16,777,216  (f16 [b][t][c])
// ---------------------------------------------------------------------------
extern "C" void kernel_launch(void* const* d_in, const int* in_sizes, int n_in,
                              void* d_out, int out_size, void* d_ws, size_t ws_size,
                              hipStream_t stream) {
    const float* inpt    = (const float*)d_in[0];
    const float* theta_w = (const float*)d_in[1];
    const float* theta_b = (const float*)d_in[2];
    const float* phi_w   = (const float*)d_in[3];
    const float* phi_b   = (const float*)d_in[4];
    const float* g_w     = (const float*)d_in[5];
    const float* g_b     = (const float*)d_in[6];
    const float* ht_w    = (const float*)d_in[7];
    const float* ht_b    = (const float*)d_in[8];
    const float* gamma   = (const float*)d_in[9];
    const float* beta    = (const float*)d_in[10];

    char* ws = (char*)d_ws;
    h16*   xT    = (h16*)(ws + 0);
    h16*   w4    = (h16*)(ws + 16777216);     // theta|phi|g rows (768 x 512)
    h16*   wHt   = w4 + 393216;               // 512 rows x 256
    float* bias3 = (float*)(ws + 17825792);
    float* Z     = (float*)(ws + 17828864);
    float* psum  = (float*)(ws + 17894400);
    float* pssq  = (float*)(ws + 17896448);
    h16*   thph  = (h16*)(ws + 17902592);     // f16 [b][t][theta||phi] ld 512
    h16*   gT    = (h16*)(ws + 34679808);     // bf16 bits [b][d][t]
    h16*   attn  = (h16*)(ws + 43068416);     // f16 [b][s][d]
    h16*   LT    = (h16*)(ws + 51457024);     // bf16 bits [b][s][t]
    h16*   hT    = (h16*)(ws + 118565888);    // f16 [b][t][c]

    const long sX  = (long)Tx * Cx;    // 1,048,576 (xT, hT)
    const long sTP = (long)Tx * 512;   // 1,048,576 (thph)
    const long sGT = (long)Dx * Tx;    //   524,288 (gT)
    const long sAT = (long)Tx * Dx;    //   524,288 (attn)
    const long sW  = (long)Tx * Tx;    // 4,194,304 (LT)

    dim3 blk(256);
    // fused input transpose + weight conversion + zero-init
    conv_prep<<<dim3(Tx / 64, Cx / 64, Bx + 1), blk, 0, stream>>>(
        inpt, xT, theta_w, phi_w, g_w, ht_w, theta_b, phi_b, g_b,
        w4, bias3, Z, psum, pssq);
    // thph[t][n] = sum_c xT[t][c]*(theta||phi)[n][c] + bias3[n]   (f16)
    // 128x64 tile: grid 8 x (16 m x 8 n) = 1024 = 4/CU
    gemm_mf<0, false, 128, 64><<<dim3(1024), blk, 0, stream>>>(
        xT, sX, Cx, w4, 0, Cx, thph, sTP, 512, nullptr, nullptr,
        Tx, 512, Cx, 16, nullptr, bias3);
    // LT[s][t] = exp(sum_d phi[s][d]*theta[t][d]) bf16; Z[t] += col sums
    // 128x128 tile: grid 8 x (16 x 16) = 2048 = 8/CU
    gemm_mf<2, false, 128, 128><<<dim3(2048), blk, 0, stream>>>(
        thph + 256, sTP, 512, thph, sTP, 512, LT, sW, Tx, nullptr, Z,
        Tx, Tx, Dx, 16, nullptr, nullptr);
    // gT[d][t] = (sum_c g_w[d][c]*xT[t][c] + g_b[d]) / Z[t]   (bf16)
    // 64x64 tile: grid 8 x (4 m x 32 n) = 1024 = 4/CU
    gemm_mf<1, false, 64, 64><<<dim3(1024), blk, 0, stream>>>(
        w4 + 512 * 512, 0, Cx, xT, sX, Cx, gT, sGT, Tx, nullptr, Z,
        Dx, Tx, Cx, 4, bias3 + 512, nullptr);
    // attn[s][d] = sum_t LT[s][t]*gT[d][t]   (bf16 in, f16 out)
    // 64x64 tile: grid 8 x (32 m x 4 n) = 1024 = 4/CU
    gemm_mf<0, true, 64, 64><<<dim3(1024), blk, 0, stream>>>(
        LT, sW, Tx, gT, sGT, Tx, attn, sAT, Dx, nullptr, nullptr,
        Tx, Dx, Tx, 32, nullptr, nullptr);
    // hT[s][c] = sum_d attn[s][d]*ht_w[c][d] + ht_b[c]; fused BN stat atomics
    // 128x64 tile: grid 8 x (16 m x 8 n) = 1024 = 4/CU (measured 674 TF cfg)
    gemm_mf<3, false, 128, 64><<<dim3(1024), blk, 0, stream>>>(
        attn, sAT, Dx, wHt, 0, Dx, hT, sX, Cx, psum, pssq,
        Tx, Cx, Dx, 16, nullptr, ht_b);
    bn_apply_T<<<dim3(Tx / 64, Cx / 64, Bx), blk, 0, stream>>>(
        xT, hT, psum, pssq, gamma, beta, (float*)d_out);
}

// Round 5
// 205.502 us; speedup vs baseline: 1.1249x; 1.0098x over previous
//
#include <hip/hip_runtime.h>
#include <hip/hip_bf16.h>
#include <math.h>

#define Bx 8
#define Cx 512
#define Dx 256
#define Tx 2048
#define EPSx 1e-5f

typedef _Float16 h16;
typedef __attribute__((ext_vector_type(8))) _Float16 h16x8;
typedef __attribute__((ext_vector_type(8))) short s16x8;
typedef __attribute__((ext_vector_type(4))) float f32x4;

typedef __attribute__((address_space(3))) unsigned int lds_u32;
typedef __attribute__((address_space(1))) const unsigned int glb_u32;

// async 16B global -> LDS DMA. ldsp must be wave-uniform; HW adds lane*16.
__device__ __forceinline__ void cp16(void* ldsp, const void* g) {
    __builtin_amdgcn_global_load_lds((glb_u32*)g, (lds_u32*)ldsp, 16, 0, 0);
}

// ---------------------------------------------------------------------------
// MFMA GEMM core: acc[m][n] = sum_k A[m][k]*B[n][k], 2-byte dtypes (f16/bf16),
// tile TM x TN (TM in {128,64}), BK=64 (0-conflict LDS layout), 4 waves,
// global_load_lds staging with XOR swizzle. Single-buffered 2-barrier K-loop:
// explicit DBUF was tried (r2) and regressed +14us (m141 order-pinning
// failure mode). Do not re-add.
// Wave layout: TM=128 -> 2x2 waves (wm=(wid&1)*64, wn=(wid>>1)*TN/2);
//              TM=64  -> 1x4 waves (wm=0, wn=wid*TN/4). Smaller tile buys
//              grid TLP (4 blocks/CU) for skinny N -- r4 change (-16us).
// Grid: 1-D, batch->XCD swizzle: b = id & 7 (pins batch to one XCD's L2);
// rr = id >> 3. Block-tile mapping (r5):
//   NFAST=0: m0 = (rr % blkArg)*TM, n0 = (rr / blkArg)*TN  (m-fastest; use
//            when per-batch working set fits 4MB L2 -- reuse is automatic)
//   NFAST=1: n0 = (rr % blkArg)*TN, m0 = (rr / blkArg)*TM  (n-fastest; use
//            when the A panel is the large re-read operand, e.g. attn's LT:
//            launch-adjacent blocks share one A panel -> L2-hit instead of
//            re-fetching 8MB/batch x4 from LLC)
// Epilogue by MODE:
//   0: f16 out, + optional biasM[row] + biasN[col]                (projection)
//   1: bf16 out = (acc + optional biasM[row]) * (1/Z[b*N+col])    (gT' = g/Z)
//   2: bf16 out = exp(acc); atomicAdd Z[b*N+col] += col sums      (logits)
//   3: f16 out = acc + biasN[col]; atomicAdd Cp[col]+=sum(v),
//      Z[col]+=sum(v^2) (fused BatchNorm stats)                   (h GEMM)
// ---------------------------------------------------------------------------
template<int MODE, bool BF, int TM, int TN, bool NFAST>
__global__ __launch_bounds__(256, 4)
void gemm_mf(const h16* __restrict__ A, long aBatch, int lda,
             const h16* __restrict__ B, long bBatch, int ldb,
             void* __restrict__ C, long cBatch, int ldc,
             float* __restrict__ Cp, float* __restrict__ Z,
             int M, int N, int K, int blkArg,
             const float* __restrict__ biasM, const float* __restrict__ biasN) {
    constexpr int WN = (TM == 128) ? TN / 2 : TN / 4;  // per-wave n-width
    constexpr int NJ = WN / 16;                        // B-frags per wave
    __shared__ h16 As[TM * 64];
    __shared__ h16 Bs[TN * 64];
    const int tid  = threadIdx.x;
    const int lane = tid & 63, wid = tid >> 6;
    const int wm = (TM == 128) ? (wid & 1) * 64 : 0;
    const int wn = (TM == 128) ? (wid >> 1) * WN : wid * WN;
    const int lm = lane & 15, quad = lane >> 4;
    const unsigned id = blockIdx.x;
    const int b = id & 7;
    const unsigned rr = id >> 3;
    int m0, n0;
    if constexpr (NFAST) {
        n0 = (rr % (unsigned)blkArg) * TN;
        m0 = (rr / (unsigned)blkArg) * TM;
    } else {
        m0 = (rr % (unsigned)blkArg) * TM;
        n0 = (rr / (unsigned)blkArg) * TN;
    }
    const h16* Ab = A + (size_t)b * aBatch + (size_t)m0 * lda;
    const h16* Bb = B + (size_t)b * bBatch + (size_t)n0 * ldb;

    const int srow  = tid >> 3;                 // row within 32-row group
    const int sclog = (tid & 7) ^ (srow & 7);   // logical k-chunk (XOR swizzle)
    char* ldsA = (char*)As + (tid & ~63) * 16;  // wave-uniform base
    char* ldsB = (char*)Bs + (tid & ~63) * 16;

    f32x4 acc[4][NJ] = {};

    for (int k0 = 0; k0 < K; k0 += 64) {
        __syncthreads();   // all waves done reading previous tile
#pragma unroll
        for (int i = 0; i < TM / 32; i++) {
            int r = srow + 32 * i;
            cp16(ldsA + i * 4096, Ab + (size_t)r * lda + k0 + sclog * 8);
        }
#pragma unroll
        for (int i = 0; i < TN / 32; i++) {
            int r = srow + 32 * i;
            cp16(ldsB + i * 4096, Bb + (size_t)r * ldb + k0 + sclog * 8);
        }
        __syncthreads();   // drains vmcnt(0): tile resident
#pragma unroll
        for (int ks = 0; ks < 2; ks++) {
            s16x8 af[4], bf4[NJ];
#pragma unroll
            for (int i = 0; i < 4; i++) {
                int row = wm + 16 * i + lm;
                int st = (ks * 4 + quad) ^ (lm & 7);
                af[i] = *(const s16x8*)(As + row * 64 + st * 8);
            }
#pragma unroll
            for (int j = 0; j < NJ; j++) {
                int row = wn + 16 * j + lm;
                int st = (ks * 4 + quad) ^ (lm & 7);
                bf4[j] = *(const s16x8*)(Bs + row * 64 + st * 8);
            }
#pragma unroll
            for (int i = 0; i < 4; i++)
#pragma unroll
                for (int j = 0; j < NJ; j++) {
                    if constexpr (BF)
                        acc[i][j] = __builtin_amdgcn_mfma_f32_16x16x32_bf16(
                            af[i], bf4[j], acc[i][j], 0, 0, 0);
                    else
                        acc[i][j] = __builtin_amdgcn_mfma_f32_16x16x32_f16(
                            __builtin_bit_cast(h16x8, af[i]),
                            __builtin_bit_cast(h16x8, bf4[j]), acc[i][j], 0, 0, 0);
                }
        }
    }

    // epilogue: C/D layout col=lane&15, row=quad*4+reg
    if constexpr (MODE == 0) {
        h16* Cb = (h16*)C + (size_t)b * cBatch;
#pragma unroll
        for (int i = 0; i < 4; i++)
#pragma unroll
            for (int j = 0; j < NJ; j++) {
                int row = m0 + wm + 16 * i + quad * 4;
                int col = n0 + wn + 16 * j + lm;
                float bN = biasN ? biasN[col] : 0.0f;
#pragma unroll
                for (int r = 0; r < 4; r++) {
                    float v = acc[i][j][r] + bN;
                    if (biasM) v += biasM[row + r];
                    Cb[(size_t)(row + r) * ldc + col] = (h16)v;
                }
            }
    } else if constexpr (MODE == 1) {
        __hip_bfloat16* Cb = (__hip_bfloat16*)C + (size_t)b * cBatch;
#pragma unroll
        for (int j = 0; j < NJ; j++) {
            int col = n0 + wn + 16 * j + lm;
            float iz = 1.0f / Z[(size_t)b * N + col];
#pragma unroll
            for (int i = 0; i < 4; i++) {
                int row = m0 + wm + 16 * i + quad * 4;
#pragma unroll
                for (int r = 0; r < 4; r++) {
                    float v = acc[i][j][r];
                    if (biasM) v += biasM[row + r];
                    Cb[(size_t)(row + r) * ldc + col] = __float2bfloat16(v * iz);
                }
            }
        }
    } else if constexpr (MODE == 2) {
        __syncthreads();                       // fragments consumed
        float* Zl = (float*)As;
        if (tid < TN) Zl[tid] = 0.0f;
        __syncthreads();
        __hip_bfloat16* Cb = (__hip_bfloat16*)C + (size_t)b * cBatch;
#pragma unroll
        for (int j = 0; j < NJ; j++) {
            int cl = wn + 16 * j + lm;
            int col = n0 + cl;
            float zp = 0.0f;
#pragma unroll
            for (int i = 0; i < 4; i++) {
                int row = m0 + wm + 16 * i + quad * 4;
#pragma unroll
                for (int r = 0; r < 4; r++) {
                    float e = __expf(acc[i][j][r]);
                    zp += e;
                    Cb[(size_t)(row + r) * ldc + col] = __float2bfloat16(e);
                }
            }
            atomicAdd(&Zl[cl], zp);
        }
        __syncthreads();
        if (tid < TN) atomicAdd(&Z[(size_t)b * N + n0 + tid], Zl[tid]);
    } else {  // MODE 3: f16 out + biasN, fused BN sum/sumsq atomics
        __syncthreads();                       // fragments consumed
        float* Sl = (float*)As;                // [0:TN) col sums
        float* Sq = Sl + TN;                   // [TN:2TN) col sumsq
        if (tid < 2 * TN) Sl[tid] = 0.0f;
        __syncthreads();
        h16* Cb = (h16*)C + (size_t)b * cBatch;
#pragma unroll
        for (int j = 0; j < NJ; j++) {
            int cl = wn + 16 * j + lm;
            int col = n0 + cl;
            float bN = biasN[col];
            float s = 0.0f, q = 0.0f;
#pragma unroll
            for (int i = 0; i < 4; i++) {
                int row = m0 + wm + 16 * i + quad * 4;
#pragma unroll
                for (int r = 0; r < 4; r++) {
                    float v = acc[i][j][r] + bN;
                    s += v;
                    q = fmaf(v, v, q);
                    Cb[(size_t)(row + r) * ldc + col] = (h16)v;
                }
            }
            atomicAdd(&Sl[cl], s);
            atomicAdd(&Sq[cl], q);
        }
        __syncthreads();
        if (tid < TN) {
            atomicAdd(&Cp[n0 + tid], Sl[tid]);
            atomicAdd(&Z[n0 + tid], Sq[tid]);
        }
    }
}

// ---------------------------------------------------------------------------
// Fused prep: z<8  -> inpt[b][c][t] fp32 -> xT[b][t][c] f16 (64x64 transpose)
//             z==8 -> weights->f16 concat, bias3, Z/psum/pssq zero-init.
// ---------------------------------------------------------------------------
__global__ __launch_bounds__(256)
void conv_prep(const float* __restrict__ inpt, h16* __restrict__ xT,
               const float* __restrict__ w0, const float* __restrict__ w1,
               const float* __restrict__ w2, const float* __restrict__ w3,
               const float* __restrict__ tb, const float* __restrict__ pb,
               const float* __restrict__ gb,
               h16* __restrict__ dst, float* __restrict__ bias3,
               float* __restrict__ Z, float* __restrict__ psum,
               float* __restrict__ pssq) {
    const int tid = threadIdx.x;
    if (blockIdx.z == 8) {
        int bx = blockIdx.y * 32 + blockIdx.x;          // 0..255
        // weights: 131072 float4 total, 512 per block
#pragma unroll
        for (int rep = 0; rep < 2; rep++) {
            int idx4 = bx * 512 + rep * 256 + tid;
            int arr = idx4 >> 15, local4 = idx4 & 32767;
            const float* srcs[4] = {w0, w1, w2, w3};
            float4 v = ((const float4*)srcs[arr])[local4];
            h16 o[4] = {(h16)v.x, (h16)v.y, (h16)v.z, (h16)v.w};
            *(uint2*)(dst + (size_t)arr * 131072 + (size_t)local4 * 4) = *(uint2*)o;
        }
        if (bx < 64) Z[bx * 256 + tid] = 0.0f;          // 16384 floats
        if (bx == 64) bias3[tid] = tb[tid];
        if (bx == 65) bias3[256 + tid] = pb[tid];
        if (bx == 66) bias3[512 + tid] = gb[tid];
        if (bx == 67) {
            psum[tid] = 0.0f; psum[tid + 256] = 0.0f;
            pssq[tid] = 0.0f; pssq[tid + 256] = 0.0f;
        }
        return;
    }
    __shared__ float lds[64][68];
    const int b = blockIdx.z;
    const int t0 = blockIdx.x * 64, c0 = blockIdx.y * 64;
    const int q = tid >> 4, k = tid & 15;
    const float* ib = inpt + (size_t)b * Cx * Tx;
#pragma unroll
    for (int i = 0; i < 4; i++) {
        int c = q + 16 * i;
        float4 v = *(const float4*)(ib + (size_t)(c0 + c) * Tx + t0 + 4 * k);
        *(float4*)&lds[c][4 * k] = v;
    }
    __syncthreads();
    h16* xb = xT + (size_t)b * Tx * Cx;
#pragma unroll
    for (int i = 0; i < 4; i++) {
        int t = q + 16 * i;
        h16 o[4];
#pragma unroll
        for (int j = 0; j < 4; j++) o[j] = (h16)lds[4 * k + j][t];
        *(uint2*)(xb + (size_t)(t0 + t) * Cx + c0 + 4 * k) = *(uint2*)o;
    }
}

// ---------------------------------------------------------------------------
// out[b][c][t] = xT(f16 residual) + gamma[c]*(hT[b][t][c]-mu)*rsig + beta[c]
// BN finalize fused; residual from the f16 transposed copy (16 MB vs 64 MB
// fp32 re-read; verified r2-r4 absmax unchanged). Work in [t][c] domain,
// transpose finished sum through LDS, write out[c][t] coalesced.
// ---------------------------------------------------------------------------
__global__ __launch_bounds__(256)
void bn_apply_T(const h16* __restrict__ xT, const h16* __restrict__ hT,
                const float* __restrict__ psum, const float* __restrict__ pssq,
                const float* __restrict__ gamma, const float* __restrict__ beta,
                float* __restrict__ out) {
    __shared__ float lds[64][68];
    const int b = blockIdx.z, t0 = blockIdx.x * 64, c0 = blockIdx.y * 64;
    const int tid = threadIdx.x, q = tid >> 4, k = tid & 15;
    const float invN = 1.0f / (float)(Bx * Tx);
    // per-thread channel params for c = c0+4k .. c0+4k+3
    float mu[4], rv[4], ga[4], be[4];
#pragma unroll
    for (int j = 0; j < 4; j++) {
        int cg = c0 + 4 * k + j;
        float m = psum[cg] * invN;
        float var = pssq[cg] * invN - m * m;
        mu[j] = m;
        rv[j] = rsqrtf(var + EPSx);
        ga[j] = gamma[cg];
        be[j] = beta[cg];
    }
    const h16* hb = hT + (size_t)b * Tx * Cx;
    const h16* xb = xT + (size_t)b * Tx * Cx;
#pragma unroll
    for (int i = 0; i < 4; i++) {
        int t = q + 16 * i;
        size_t off = (size_t)(t0 + t) * Cx + c0 + 4 * k;
        uint2 hraw = *(const uint2*)(hb + off);
        uint2 xraw = *(const uint2*)(xb + off);
        const h16* hp = (const h16*)&hraw;
        const h16* xp = (const h16*)&xraw;
        float o[4];
#pragma unroll
        for (int j = 0; j < 4; j++)
            o[j] = (float)xp[j] + ga[j] * ((float)hp[j] - mu[j]) * rv[j] + be[j];
        *(float4*)&lds[t][4 * k] = *(float4*)o;
    }
    __syncthreads();
    float* ob = out + (size_t)b * Cx * Tx;
#pragma unroll
    for (int i = 0; i < 4; i++) {
        int c = q + 16 * i;
        int cg = c0 + c;
        float4 o;
        o.x = lds[4 * k + 0][c];
        o.y = lds[4 * k + 1][c];
        o.z = lds[4 * k + 2][c];
        o.w = lds[4 * k + 3][c];
        *(float4*)(ob + (size_t)cg * Tx + t0 + 4 * k) = o;
    }
}

// ---------------------------------------------------------------------------
// Pipeline (51.6 GF total), all GEMMs at >=4 blocks/CU:
//   1. prep:   xT = transpose(inpt) f16; weights->f16; zero Z/psum/pssq
//   2. proj:   thph[t][0:512) = xT.(theta|phi)^T + bias   (8.6 GF, 128x64)
//   3. logits: LT[s][t]=exp(phi[s].theta[t]); Z[t]+=csum  (17.2 GF, 128x128)
//   4. gT':    gT[d][t]=(g_w[d].xT[t]+g_b[d])/Z[t] bf16   (4.3 GF, 64x64)
//   5. attn:   attn[s][d]=sum_t LT[s][t]*gT[d][t] f16     (17.2 GF, 64x64,
//              n-fastest mapping: LT panel L2-reuse, r5)
//   6. h:      hT[s][c]=attn[s].ht_w[c]+ht_b[c]; BN stats (4.3 GF, 128x64)
//   7. bn_apply (residual from xT f16)
//
// Workspace (bytes, total ~130 MiB):
//   xT    @0             16,777,216  (f16 [b][t][c]; live to the end)
//   w4    @16,777,216     1,048,576  (theta|phi|g f16 768x512; wHt 512x256)
//   bias3 @17,825,792         3,072  (theta_b||phi_b||g_b)
//   Z     @17,828,864        65,536  (fp32 exp-row-sums [b][t])
//   psum  @17,894,400         2,048  (fp32 BN channel sums)
//   pssq  @17,896,448         2,048
//   thph  @17,902,592    16,777,216  (f16 [b][t][theta||phi], ld 512)
//   gT    @34,679,808     8,388,608  (bf16 [b][d][t] = g/Z, ld 2048)
//   attn  @43,068,416     8,388,608  (f16 [b][s][d], ld 256)
//   LT    @51,457,024    67,108,864  (bf16 exp-logits [b][s][t])
//   hT    @118,565,888   16,777,216  (f16 [b][t][c])
// ---------------------------------------------------------------------------
extern "C" void kernel_launch(void* const* d_in, const int* in_sizes, int n_in,
                              void* d_out, int out_size, void* d_ws, size_t ws_size,
                              hipStream_t stream) {
    const float* inpt    = (const float*)d_in[0];
    const float* theta_w = (const float*)d_in[1];
    const float* theta_b = (const float*)d_in[2];
    const float* phi_w   = (const float*)d_in[3];
    const float* phi_b   = (const float*)d_in[4];
    const float* g_w     = (const float*)d_in[5];
    const float* g_b     = (const float*)d_in[6];
    const float* ht_w    = (const float*)d_in[7];
    const float* ht_b    = (const float*)d_in[8];
    const float* gamma   = (const float*)d_in[9];
    const float* beta    = (const float*)d_in[10];

    char* ws = (char*)d_ws;
    h16*   xT    = (h16*)(ws + 0);
    h16*   w4    = (h16*)(ws + 16777216);     // theta|phi|g rows (768 x 512)
    h16*   wHt   = w4 + 393216;               // 512 rows x 256
    float* bias3 = (float*)(ws + 17825792);
    float* Z     = (float*)(ws + 17828864);
    float* psum  = (float*)(ws + 17894400);
    float* pssq  = (float*)(ws + 17896448);
    h16*   thph  = (h16*)(ws + 17902592);     // f16 [b][t][theta||phi] ld 512
    h16*   gT    = (h16*)(ws + 34679808);     // bf16 bits [b][d][t]
    h16*   attn  = (h16*)(ws + 43068416);     // f16 [b][s][d]
    h16*   LT    = (h16*)(ws + 51457024);     // bf16 bits [b][s][t]
    h16*   hT    = (h16*)(ws + 118565888);    // f16 [b][t][c]

    const long sX  = (long)Tx * Cx;    // 1,048,576 (xT, hT)
    const long sTP = (long)Tx * 512;   // 1,048,576 (thph)
    const long sGT = (long)Dx * Tx;    //   524,288 (gT)
    const long sAT = (long)Tx * Dx;    //   524,288 (attn)
    const long sW  = (long)Tx * Tx;    // 4,194,304 (LT)

    dim3 blk(256);
    // fused input transpose + weight conversion + zero-init
    conv_prep<<<dim3(Tx / 64, Cx / 64, Bx + 1), blk, 0, stream>>>(
        inpt, xT, theta_w, phi_w, g_w, ht_w, theta_b, phi_b, g_b,
        w4, bias3, Z, psum, pssq);
    // thph[t][n] = sum_c xT[t][c]*(theta||phi)[n][c] + bias3[n]   (f16)
    // 128x64 tile: grid 8 x (16 m x 8 n) = 1024 = 4/CU
    gemm_mf<0, false, 128, 64, false><<<dim3(1024), blk, 0, stream>>>(
        xT, sX, Cx, w4, 0, Cx, thph, sTP, 512, nullptr, nullptr,
        Tx, 512, Cx, 16, nullptr, bias3);
    // LT[s][t] = exp(sum_d phi[s][d]*theta[t][d]) bf16; Z[t] += col sums
    // 128x128 tile: grid 8 x (16 x 16) = 2048 = 8/CU
    gemm_mf<2, false, 128, 128, false><<<dim3(2048), blk, 0, stream>>>(
        thph + 256, sTP, 512, thph, sTP, 512, LT, sW, Tx, nullptr, Z,
        Tx, Tx, Dx, 16, nullptr, nullptr);
    // gT[d][t] = (sum_c g_w[d][c]*xT[t][c] + g_b[d]) / Z[t]   (bf16)
    // 64x64 tile: grid 8 x (4 m x 32 n) = 1024 = 4/CU
    gemm_mf<1, false, 64, 64, false><<<dim3(1024), blk, 0, stream>>>(
        w4 + 512 * 512, 0, Cx, xT, sX, Cx, gT, sGT, Tx, nullptr, Z,
        Dx, Tx, Cx, 4, bias3 + 512, nullptr);
    // attn[s][d] = sum_t LT[s][t]*gT[d][t]   (bf16 in, f16 out)
    // 64x64 tile, n-fastest: grid 8 x (4 n x 32 m) = 1024 = 4/CU.
    // Adjacent blocks share the 256KB LT panel (L2-hit); gT (1MB/batch) is
    // L2-resident. LT LLC re-reads drop 4x (r5).
    gemm_mf<0, true, 64, 64, true><<<dim3(1024), blk, 0, stream>>>(
        LT, sW, Tx, gT, sGT, Tx, attn, sAT, Dx, nullptr, nullptr,
        Tx, Dx, Tx, 4, nullptr, nullptr);
    // hT[s][c] = sum_d attn[s][d]*ht_w[c][d] + ht_b[c]; fused BN stat atomics
    // 128x64 tile: grid 8 x (16 m x 8 n) = 1024 = 4/CU
    gemm_mf<3, false, 128, 64, false><<<dim3(1024), blk, 0, stream>>>(
        attn, sAT, Dx, wHt, 0, Dx, hT, sX, Cx, psum, pssq,
        Tx, Cx, Dx, 16, nullptr, ht_b);
    bn_apply_T<<<dim3(Tx / 64, Cx / 64, Bx), blk, 0, stream>>>(
        xT, hT, psum, pssq, gamma, beta, (float*)d_out);
}